// Round 6
// baseline (74.869 us; speedup 1.0000x reference)
//
#include <hip/hip_runtime.h>

// out[b] = sum_g exp(-(||x_b||^2+||c_g||^2-2 x_b.c_g)/2) * w[g]
// B=16384, G=8192, D=64 fp32.
// v6: split-bf16 3-pass MFMA, zero LDS/zero barriers. R5 post-mortem: stalls
// are B-load latency (X streaming evicts B from L2 -> L3/HBM ~500-900cy) with
// only 2 waves/SIMD of TLP and depth-1 prefetch. Fixes:
//  - 12 waves/CU: GSPLIT=12 (uneven 22/21 col-tile split), grid=768=3 blk/CU
//    exactly one round; __launch_bounds__(256,3) (per-SIMD pool=512 regs).
//  - B prefetch distance 2 f-steps, 4 static register slots (rule #20).
//  - X loads nontemporal -> stop evicting B (2MB) from L2.
//  - single acc set (E/O dbuf was neutral; TLP now does the overlap).

typedef __attribute__((ext_vector_type(8))) short short8v;
typedef __attribute__((ext_vector_type(16))) float f32x16;
typedef __attribute__((ext_vector_type(4))) float f32x4;
typedef unsigned short u16;
typedef unsigned int u32;

#define L2E   1.4426950408889634f
#define NHL2E 0.72134752044448170f   // log2(e)/2
#define GP 12                        // G split parts (22/21 tiles of 32 cols)

__device__ __forceinline__ u16 f2bf(float x){
  u32 u = __float_as_uint(x);
  return (u16)((u + 0x7FFFu + ((u >> 16) & 1u)) >> 16);   // RNE
}
__device__ __forceinline__ float bf2f(u16 h){ return __uint_as_float(((u32)h) << 16); }

#define MFMA(a,b,c) __builtin_amdgcn_mfma_f32_32x32x16_bf16(a,b,c,0,0,0)

// ---- one-time: C [G][64] fp32 -> hi/lo bf16 in fragment order + (cn,w) ----
// frag unit (cg=g/32, f): 64 lanes x 16B; byte base = cg*4096 + f*1024 + l*16
__global__ __launch_bounds__(256)
void convert_C(const float* __restrict__ C, const float* __restrict__ W,
               u16* __restrict__ Chi, u16* __restrict__ Clo,
               float2* __restrict__ cw, int G){
  int idx = blockIdx.x*256 + threadIdx.x;
  int g = idx >> 2, f = idx & 3;
  if (g >= G) return;
  const float* row = C + (size_t)g*64 + f*16;
  int cg = g >> 5, cl = g & 31;
  float norm = 0.f;
  u16 hb[16], lb[16];
  #pragma unroll
  for (int q=0; q<4; q++){
    float4 v = *(const float4*)(row + q*4);
    float xv[4] = {v.x, v.y, v.z, v.w};
    #pragma unroll
    for (int e=0; e<4; e++){
      float x = xv[e];
      norm = fmaf(x, x, norm);
      u16 hh = f2bf(x); hb[q*4+e] = hh;
      lb[q*4+e] = f2bf(x - bf2f(hh));
    }
  }
  norm += __shfl_xor(norm, 1);
  norm += __shfl_xor(norm, 2);
  size_t u = ((size_t)(cg*4 + f)*64 + cl)*8;
  *(short8v*)(Chi + u)        = *(short8v*)hb;        // h=0 (k 0..7)
  *(short8v*)(Chi + u + 256)  = *(short8v*)(hb + 8);  // h=1 (k 8..15)
  *(short8v*)(Clo + u)        = *(short8v*)lb;
  *(short8v*)(Clo + u + 256)  = *(short8v*)(lb + 8);
  if (f == 0) cw[g] = make_float2(-NHL2E*norm, W[g]);
}

// 6 MFMA for one f-step: 2 rowfrag chains x 3 passes (hh, hl, lh)
#define FSTEP(F, BH, BL) do {                    \
    a0 = MFMA(ah[0][F], BH, a0);                 \
    a1 = MFMA(ah[1][F], BH, a1);                 \
    a0 = MFMA(ah[0][F], BL, a0);                 \
    a1 = MFMA(ah[1][F], BL, a1);                 \
    a0 = MFMA(al[0][F], BH, a0);                 \
    a1 = MFMA(al[1][F], BH, a1);                 \
  } while(0)

__global__ __launch_bounds__(256, 3)
void rbf_mfma(const float* __restrict__ X, const u16* __restrict__ Chi,
              const u16* __restrict__ Clo, const float2* __restrict__ cw,
              float* __restrict__ out){
  const int tid = threadIdx.x;
  const int l  = tid & 63;
  const int cl = l & 31;
  const int h  = l >> 5;
  const int w  = tid >> 6;
  const int b  = blockIdx.x;
  const int gp = b % GP;
  const int rows0 = (b / GP) * 256 + w * 64;

  // col-tile range: 256 tiles of 32 cols over G; gp 0..3 get 22, 4..11 get 21
  const int t0  = gp * 21 + (gp < 4 ? gp : 4);
  const int ntl = (gp < 4) ? 22 : 21;

  // ---- A: 64 rows hi/lo bf16 in regs; nontemporal X loads (keep L2 for B) --
  short8v ah[2][4], al[2][4];
  float xn[2];
  #pragma unroll
  for (int rf=0; rf<2; rf++){
    const float* xr = X + (size_t)(rows0 + rf*32 + cl)*64;
    float s = 0.f;
    #pragma unroll
    for (int f=0; f<4; f++){
      f32x4 v0 = __builtin_nontemporal_load((const f32x4*)(xr + f*16 + h*8));
      f32x4 v1 = __builtin_nontemporal_load((const f32x4*)(xr + f*16 + h*8 + 4));
      float xv[8] = {v0.x,v0.y,v0.z,v0.w,v1.x,v1.y,v1.z,v1.w};
      u16 hb[8], lb[8];
      #pragma unroll
      for (int e=0;e<8;e++){
        float x = xv[e];
        s = fmaf(x, x, s);
        u16 hh = f2bf(x); hb[e]=hh;
        lb[e] = f2bf(x - bf2f(hh));
      }
      ah[rf][f] = *(short8v*)hb;
      al[rf][f] = *(short8v*)lb;
    }
    s += __shfl_xor(s, 32);
    xn[rf] = -NHL2E * s;
  }

  // B stream: byte addr = T*4096 + f*1024 + l*16 (fragment-ordered Chi/Clo)
  const char* baseH = (const char*)Chi + (size_t)l*16;
  const char* baseL = (const char*)Clo + (size_t)l*16;

  // 4 static slots, prefetch distance 2 f-steps:
  //   f=0: use s0, load s2<-(T,2);  f=1: use s1, load s3<-(T,3)
  //   f=2: use s2, load s0<-(T+1,0); f=3: use s3, load s1<-(T+1,1)
  short8v bh0,bh1,bh2,bh3, bl0,bl1,bl2,bl3;
  {
    const size_t o0 = (size_t)t0*4096;
    bh0 = *(const short8v*)(baseH + o0);
    bl0 = *(const short8v*)(baseL + o0);
    bh1 = *(const short8v*)(baseH + o0 + 1024);
    bl1 = *(const short8v*)(baseL + o0 + 1024);
  }

  float racc0[16], racc1[16];
  #pragma unroll
  for (int r=0;r<16;r++){ racc0[r]=0.f; racc1[r]=0.f; }

  #pragma unroll 1
  for (int ti=0; ti<ntl; ++ti){
    const int T  = t0 + ti;
    const int Tn = (ti+1 < ntl) ? T + 1 : t0;   // tail prefetch wraps (harmless)
    const size_t oT = (size_t)T*4096, oN = (size_t)Tn*4096;
    const float2 cwv = cw[T*32 + cl];

    f32x16 a0 = {}, a1 = {};
    __builtin_amdgcn_s_setprio(1);
    bh2 = *(const short8v*)(baseH + oT + 2048);
    bl2 = *(const short8v*)(baseL + oT + 2048);
    FSTEP(0, bh0, bl0);
    bh3 = *(const short8v*)(baseH + oT + 3072);
    bl3 = *(const short8v*)(baseL + oT + 3072);
    FSTEP(1, bh1, bl1);
    bh0 = *(const short8v*)(baseH + oN);
    bl0 = *(const short8v*)(baseL + oN);
    FSTEP(2, bh2, bl2);
    bh1 = *(const short8v*)(baseH + oN + 1024);
    bl1 = *(const short8v*)(baseL + oN + 1024);
    FSTEP(3, bh3, bl3);
    __builtin_amdgcn_s_setprio(0);

    // ---- epilogue: racc += 2^(L2E*dot + cn) * w ----
    #pragma unroll
    for (int r=0;r<16;++r){
      racc0[r] = fmaf(__builtin_amdgcn_exp2f(fmaf(a0[r], L2E, cwv.x)), cwv.y, racc0[r]);
      racc1[r] = fmaf(__builtin_amdgcn_exp2f(fmaf(a1[r], L2E, cwv.x)), cwv.y, racc1[r]);
    }
  }

  // ---- reduce over 32 col-lanes, fold 2^xn, one atomic per row ----
  #pragma unroll
  for (int rf=0; rf<2; rf++){
    #pragma unroll
    for (int r=0;r<16;r++){
      float v = rf ? racc1[r] : racc0[r];
      v += __shfl_xor(v, 1);
      v += __shfl_xor(v, 2);
      v += __shfl_xor(v, 4);
      v += __shfl_xor(v, 8);
      v += __shfl_xor(v, 16);
      const int rit = (r&3) + 8*(r>>2) + 4*h;
      const float xnv = __shfl(xn[rf], rit);
      if (cl == 0)
        atomicAdd(&out[rows0 + rf*32 + rit], v * __builtin_amdgcn_exp2f(xnv));
    }
  }
}

extern "C" void kernel_launch(void* const* d_in, const int* in_sizes, int n_in,
                              void* d_out, int out_size, void* d_ws, size_t ws_size,
                              hipStream_t stream) {
  const float* X = (const float*)d_in[0];   // [B,64]
  const float* C = (const float*)d_in[1];   // [G,64]
  const float* W = (const float*)d_in[2];   // [G]
  float* out = (float*)d_out;               // [B]
  const int B = in_sizes[0] / 64;
  const int G = in_sizes[2];

  u16* Chi = (u16*)d_ws;                         // 1 MB
  u16* Clo = Chi + (size_t)G*64;                 // 1 MB
  float2* cw = (float2*)(Clo + (size_t)G*64);    // 64 KB

  hipMemsetAsync(out, 0, (size_t)B*sizeof(float), stream);
  convert_C<<<(G*4)/256, 256, 0, stream>>>(C, W, Chi, Clo, cw, G);
  rbf_mfma<<<(B/256)*GP, 256, 0, stream>>>(X, Chi, Clo, cw, out);
}

// Round 7
// 69.281 us; speedup vs baseline: 1.0807x; 1.0807x over previous
//
#include <hip/hip_runtime.h>

// out[b] = sum_g exp(-(||x_b||^2+||c_g||^2-2 x_b.c_g)/2) * w[g]
// B=16384, G=8192, D=64 fp32.
// v7: split-bf16 3-pass MFMA, zero LDS/zero barriers, FULL-TILE register
// prefetch. R5/R6 post-mortem: the ~40% dead time is B-load latency exposed
// by depth-1 prefetch (~190cy cover vs 200-500cy L2/L3); R6's TLP fix made
// the allocator sink the loads (VGPR 116->84). Now: two static B register
// sets (even/odd tiles), 8 loads for tile t+1 interleaved into tile t's 24
// MFMAs -> ~700cy cover. ~212 VGPR at __launch_bounds__(256,2).
// Grid 512 = 2 blocks/CU exactly; 32 tiles of 32 cols per wave.

typedef __attribute__((ext_vector_type(8))) short short8v;
typedef __attribute__((ext_vector_type(16))) float f32x16;
typedef unsigned short u16;
typedef unsigned int u32;

#define L2E   1.4426950408889634f
#define NHL2E 0.72134752044448170f   // log2(e)/2
#define GSPLIT 8                     // 1024 cols per wave sweep

__device__ __forceinline__ u16 f2bf(float x){
  u32 u = __float_as_uint(x);
  return (u16)((u + 0x7FFFu + ((u >> 16) & 1u)) >> 16);   // RNE
}
__device__ __forceinline__ float bf2f(u16 h){ return __uint_as_float(((u32)h) << 16); }

#define MFMA(a,b,c) __builtin_amdgcn_mfma_f32_32x32x16_bf16(a,b,c,0,0,0)

// ---- one-time: C [G][64] fp32 -> hi/lo bf16 in fragment order + (cn,w) ----
// frag unit (cg=g/32, f): byte base = cg*4096 + f*1024 + l*16
__global__ __launch_bounds__(256)
void convert_C(const float* __restrict__ C, const float* __restrict__ W,
               u16* __restrict__ Chi, u16* __restrict__ Clo,
               float2* __restrict__ cw, int G){
  int idx = blockIdx.x*256 + threadIdx.x;
  int g = idx >> 2, f = idx & 3;
  if (g >= G) return;
  const float* row = C + (size_t)g*64 + f*16;
  int cg = g >> 5, cl = g & 31;
  float norm = 0.f;
  u16 hb[16], lb[16];
  #pragma unroll
  for (int q=0; q<4; q++){
    float4 v = *(const float4*)(row + q*4);
    float xv[4] = {v.x, v.y, v.z, v.w};
    #pragma unroll
    for (int e=0; e<4; e++){
      float x = xv[e];
      norm = fmaf(x, x, norm);
      u16 hh = f2bf(x); hb[q*4+e] = hh;
      lb[q*4+e] = f2bf(x - bf2f(hh));
    }
  }
  norm += __shfl_xor(norm, 1);
  norm += __shfl_xor(norm, 2);
  size_t u = ((size_t)(cg*4 + f)*64 + cl)*8;
  *(short8v*)(Chi + u)        = *(short8v*)hb;        // h=0 (k 0..7)
  *(short8v*)(Chi + u + 256)  = *(short8v*)(hb + 8);  // h=1 (k 8..15)
  *(short8v*)(Clo + u)        = *(short8v*)lb;
  *(short8v*)(Clo + u + 256)  = *(short8v*)(lb + 8);
  if (f == 0) cw[g] = make_float2(-NHL2E*norm, W[g]);
}

__global__ __launch_bounds__(256, 2)
void rbf_mfma(const float* __restrict__ X, const u16* __restrict__ Chi,
              const u16* __restrict__ Clo, const float2* __restrict__ cw,
              float* __restrict__ out){
  const int tid = threadIdx.x;
  const int l  = tid & 63;
  const int cl = l & 31;
  const int h  = l >> 5;
  const int w  = tid >> 6;
  const int b  = blockIdx.x;
  const int gp = b & 7;                  // 4 waves share gp -> L1/L2 B-sharing
  const int rows0 = ((b >> 3)*4 + w) * 64;

  // ---- A: 64 rows (2 rowfrags) hi/lo bf16 in registers ----
  short8v ah[2][4], al[2][4];
  float xn[2];
  #pragma unroll
  for (int rf=0; rf<2; rf++){
    const float* xr = X + (size_t)(rows0 + rf*32 + cl)*64;
    float s = 0.f;
    #pragma unroll
    for (int f=0; f<4; f++){
      float4 v0 = *(const float4*)(xr + f*16 + h*8);
      float4 v1 = *(const float4*)(xr + f*16 + h*8 + 4);
      float xv[8] = {v0.x,v0.y,v0.z,v0.w,v1.x,v1.y,v1.z,v1.w};
      u16 hb[8], lb[8];
      #pragma unroll
      for (int e=0;e<8;e++){
        float x = xv[e];
        s = fmaf(x, x, s);
        u16 hh = f2bf(x); hb[e]=hh;
        lb[e] = f2bf(x - bf2f(hh));
      }
      ah[rf][f] = *(short8v*)hb;
      al[rf][f] = *(short8v*)lb;
    }
    s += __shfl_xor(s, 32);
    xn[rf] = -NHL2E * s;
  }

  // B stream: byte addr = t*4096 + f*1024 + l*16 within this gp part
  const char* baseH = (const char*)Chi + (size_t)gp*131072 + (size_t)l*16;
  const char* baseL = (const char*)Clo + (size_t)gp*131072 + (size_t)l*16;
  const float2* cwp = cw + gp*1024 + cl;

  // two static B register sets (even/odd tiles), full tile each
  short8v bhA[4], blA[4], bhB[4], blB[4];
  #pragma unroll
  for (int f=0; f<4; f++){
    bhA[f] = *(const short8v*)(baseH + f*1024);
    blA[f] = *(const short8v*)(baseL + f*1024);
  }

  float racc0[16], racc1[16];
  #pragma unroll
  for (int r=0;r<16;r++){ racc0[r]=0.f; racc1[r]=0.f; }

  // tile T: use CUR set, prefetch T+1 into NXT set interleaved with MFMAs
  #define TILE(T, CUR_H, CUR_L, NXT_H, NXT_L) do {                          \
    const size_t oN = (size_t)(((T)+1) & 31)*4096;                          \
    const float2 cwv = cwp[(T)*32];                                         \
    f32x16 a0 = {}, a1 = {};                                                \
    __builtin_amdgcn_s_setprio(1);                                          \
    _Pragma("unroll")                                                       \
    for (int f=0; f<4; ++f){                                                \
      NXT_H[f] = *(const short8v*)(baseH + oN + f*1024);                    \
      a0 = MFMA(ah[0][f], CUR_H[f], a0);                                    \
      a1 = MFMA(ah[1][f], CUR_H[f], a1);                                    \
      NXT_L[f] = *(const short8v*)(baseL + oN + f*1024);                    \
      a0 = MFMA(ah[0][f], CUR_L[f], a0);                                    \
      a1 = MFMA(ah[1][f], CUR_L[f], a1);                                    \
      a0 = MFMA(al[0][f], CUR_H[f], a0);                                    \
      a1 = MFMA(al[1][f], CUR_H[f], a1);                                    \
    }                                                                       \
    __builtin_amdgcn_s_setprio(0);                                          \
    _Pragma("unroll")                                                       \
    for (int r=0;r<16;++r){                                                 \
      racc0[r] = fmaf(__builtin_amdgcn_exp2f(fmaf(a0[r], L2E, cwv.x)),      \
                      cwv.y, racc0[r]);                                     \
      racc1[r] = fmaf(__builtin_amdgcn_exp2f(fmaf(a1[r], L2E, cwv.x)),      \
                      cwv.y, racc1[r]);                                     \
    }                                                                       \
  } while(0)

  #pragma unroll 1
  for (int tp = 0; tp < 16; ++tp){
    TILE(2*tp,     bhA, blA, bhB, blB);   // even tile: use A, prefetch into B
    TILE(2*tp + 1, bhB, blB, bhA, blA);   // odd tile: use B, prefetch into A
  }
  #undef TILE

  // ---- reduce over 32 col-lanes, fold 2^xn, one atomic per row ----
  #pragma unroll
  for (int rf=0; rf<2; rf++){
    #pragma unroll
    for (int r=0;r<16;r++){
      float v = rf ? racc1[r] : racc0[r];
      v += __shfl_xor(v, 1);
      v += __shfl_xor(v, 2);
      v += __shfl_xor(v, 4);
      v += __shfl_xor(v, 8);
      v += __shfl_xor(v, 16);
      const int rit = (r&3) + 8*(r>>2) + 4*h;
      const float xnv = __shfl(xn[rf], rit);
      if (cl == 0)
        atomicAdd(&out[rows0 + rf*32 + rit], v * __builtin_amdgcn_exp2f(xnv));
    }
  }
}

extern "C" void kernel_launch(void* const* d_in, const int* in_sizes, int n_in,
                              void* d_out, int out_size, void* d_ws, size_t ws_size,
                              hipStream_t stream) {
  const float* X = (const float*)d_in[0];   // [B,64]
  const float* C = (const float*)d_in[1];   // [G,64]
  const float* W = (const float*)d_in[2];   // [G]
  float* out = (float*)d_out;               // [B]
  const int B = in_sizes[0] / 64;
  const int G = in_sizes[2];

  u16* Chi = (u16*)d_ws;                         // 1 MB
  u16* Clo = Chi + (size_t)G*64;                 // 1 MB
  float2* cw = (float2*)(Clo + (size_t)G*64);    // 64 KB

  hipMemsetAsync(out, 0, (size_t)B*sizeof(float), stream);
  convert_C<<<(G*4)/256, 256, 0, stream>>>(C, W, Chi, Clo, cw, G);
  rbf_mfma<<<(B/256)*GSPLIT, 256, 0, stream>>>(X, Chi, Clo, cw, out);
}